// Round 6
// baseline (99614.502 us; speedup 1.0000x reference)
//
#include <hip/hip_runtime.h>
#include <stdint.h>

#define TS 4096
#define NEG_VAL -1000000000.0f

typedef _Float16 h2 __attribute__((ext_vector_type(2)));
typedef unsigned long long u64t;

// ---------------- workspace layout (bytes) ----------------
#define GI0_OFF   ((size_t)0)                          // 4096*1536*4 = 25165824
#define H1_OFF    ((size_t)TS*1536*4)                  // 4096*512*4  = 8388608
#define R0_OFF    (H1_OFF + (size_t)TS*512*4)          // 16 slots * 256 words * 8B = 32768
#define R1_OFF    (R0_OFF + 32768)                     // 32768
#define GIR_OFF   (R1_OFF + 32768)                     // 16 * 768 * 8 = 98304
#define PROGS_OFF (GIR_OFF + 98304)                    // 192 u32 -> 1024
#define PROGH_OFF (PROGS_OFF + 1024)                   // 64 u32  -> 256
#define TICK_OFF  (PROGH_OFF + 256)
#define WS_NEED   (TICK_OFF + 64)

// ---------------- helpers ----------------
static __device__ __forceinline__ u64t ld_a64(const u64t* p){
  return __hip_atomic_load(p, __ATOMIC_RELAXED, __HIP_MEMORY_SCOPE_AGENT);
}
static __device__ __forceinline__ void st_a64(u64t* p, u64t v){
  __hip_atomic_store(p, v, __ATOMIC_RELAXED, __HIP_MEMORY_SCOPE_AGENT);
}
static __device__ __forceinline__ unsigned ld_u32(const unsigned* p){
  return __hip_atomic_load(p, __ATOMIC_RELAXED, __HIP_MEMORY_SCOPE_AGENT);
}
static __device__ __forceinline__ void st_u32(unsigned* p, unsigned v){
  __hip_atomic_store(p, v, __ATOMIC_RELAXED, __HIP_MEMORY_SCOPE_AGENT);
}
static __device__ __forceinline__ float sigmoidf_(float x){
  return 1.0f / (1.0f + __expf(-x));
}
static __device__ __forceinline__ float tanhf_(float x){
  float ax = fabsf(x);
  float e  = __expf(-2.0f*ax);
  float t  = (1.0f - e) / (1.0f + e);
  return copysignf(t, x);
}
static __device__ __forceinline__ uint32_t pack2h(float a, float b){
  _Float16 ha = (_Float16)a, hb = (_Float16)b;
  unsigned short ua = __builtin_bit_cast(unsigned short, ha);
  unsigned short ub = __builtin_bit_cast(unsigned short, hb);
  return (uint32_t)ua | ((uint32_t)ub << 16);
}
static __device__ __forceinline__ h2 u2h2(uint32_t u){ return __builtin_bit_cast(h2, u); }
static __device__ __forceinline__ unsigned tg(u64t v){ return (unsigned)(v>>32); }

template<int CTRL>
static __device__ __forceinline__ float dppx(float x){
  return __int_as_float(__builtin_amdgcn_update_dpp(0, __float_as_int(x), CTRL, 0xF, 0xF, true));
}
static __device__ __forceinline__ float qsum8(float x){
  x += dppx<0xB1>(x);              // xor 1
  x += dppx<0x4E>(x);              // xor 2
  x += __shfl_xor(x, 4, 64);       // xor 4
  return x;
}
static __device__ __forceinline__ int wave_min(int v){
  #pragma unroll
  for (int off=32; off; off>>=1){ int o = __shfl_xor(v, off, 64); v = o<v?o:v; }
  return v;
}

#if __has_builtin(__builtin_amdgcn_fdot2)
#define FDOT2(a,b,c) __builtin_amdgcn_fdot2((a),(b),(c),false)
#else
static __device__ __forceinline__ float FDOT2(h2 a, h2 b, float c){
  return c + (float)a[0]*(float)b[0] + (float)a[1]*(float)b[1];
}
#endif

// poll 32 tagged words (tag==want => payload valid); per-word straggler retry.
static __device__ __forceinline__ void poll32(const u64t* base, unsigned want,
                                              u64t (&d)[32], long* bd){
  #pragma unroll
  for (int i=0;i<32;++i) d[i] = ld_a64(base+i);
  for(;;){
    bool ok = true;
    #pragma unroll
    for (int i=0;i<32;++i) ok = ok && (tg(d[i])==want);
    if (ok) return;
    if (--(*bd) < 0) return;
    #pragma unroll
    for (int i=0;i<32;++i) if (tg(d[i])!=want) d[i] = ld_a64(base+i);
  }
}
// 3 rows x 32 h2 against 32 tagged words (payload = 2 f16)
static __device__ __forceinline__ void dot96t(const h2 (&w)[96], const u64t (&d)[32],
                                              float& s0, float& s1, float& s2){
  float a0=0.f, a1=0.f, a2=0.f;
  #pragma unroll
  for (int i=0;i<32;++i){
    h2 v = u2h2((uint32_t)d[i]);
    a0 = FDOT2(w[i],    v, a0);
    a1 = FDOT2(w[32+i], v, a1);
    a2 = FDOT2(w[64+i], v, a2);
  }
  s0=a0; s1=a1; s2=a2;
}
// load a 64-col (32 h2) slice of a weight row, f32 -> f16
static __device__ __forceinline__ void loadseg(h2* dst, const float* rowcol){
  const float4* p = (const float4*)rowcol;
  #pragma unroll
  for (int k=0;k<16;++k){
    float4 v = p[k];
    dst[2*k]   = h2{(_Float16)v.x, (_Float16)v.y};
    dst[2*k+1] = h2{(_Float16)v.z, (_Float16)v.w};
  }
}

// ================= fused kernel: 256 WGs x 512 thr, barrier-free scan =================
// WG 0..7  : layer0 (Whh0; 64 outputs each; 8 lanes/output; w[96] in VGPR)
// WG 8..15 : layer1 (Whh1; gi1 from gir)
// WG 16..23: gi1 helpers (Wih1; publish tagged gir words)
// WG 24..255: FC GEMM workers (128x64 tiles, ticketed, gated on progH)
// Ring word convention: value of step t carries tag (t+2); hprev seed = tag 1 at slot 15.
__global__ __launch_bounds__(512,1) void actor_fused(
    const float* __restrict__ hprev,
    const int*   __restrict__ mask,
    const float* __restrict__ Whh0,
    const float* __restrict__ bhh0,
    const float* __restrict__ Wih1,
    const float* __restrict__ Whh1,
    const float* __restrict__ bih1,
    const float* __restrict__ bhh1,
    const float* __restrict__ Wfc,
    const float* __restrict__ bfc,
    const float* __restrict__ gi0,
    float* __restrict__ H1,
    u64t* ring0, u64t* ring1, u64t* gir,
    unsigned* progS, unsigned* progH, unsigned* ticket,
    float* __restrict__ out, float* __restrict__ hnext)
{
  const int wg   = blockIdx.x;
  const int tid  = threadIdx.x;
  const int wv   = tid >> 6;
  const int lane = tid & 63;
  __shared__ __align__(16) float lds[6408];   // FC staging only
  long bd = 1L<<24;

  if (wg < 8){
    // ===================== layer 0 =====================
    const int o = wg*64 + (tid>>3);
    const int j = tid&7;
    h2 w[96];
    loadseg(&w[0],  Whh0 + (size_t)o*512         + 64*j);
    loadseg(&w[32], Whh0 + (size_t)(512+o)*512   + 64*j);
    loadseg(&w[64], Whh0 + (size_t)(1024+o)*512  + 64*j);
    const float br=bhh0[o], bz=bhh0[512+o], bn=bhh0[1024+o];
    float hreg = hprev[o];
    if ((tid&15)==0)
      st_a64(ring0 + 15*256 + (o>>1), ((u64t)1<<32) | pack2h(hprev[o], hprev[o+1]));

    for (int t=0; t<TS; ++t){
      if ((t&3)==0){
        if (lane==0) st_u32(progS + wg*8 + wv, (unsigned)t);
        if (t>=16){
          const int need = t-12;
          for(;;){
            int v0 = (int)ld_u32(progS + lane);         // L0 rows 0..7
            int v1 = (int)ld_u32(progS + 128 + lane);   // helper rows 16..23
            if (wave_min(v0<v1?v0:v1) >= need) break;
            if (--bd<0) break;
          }
        }
      }
      const float* gp = gi0 + (size_t)t*1536;           // includes bih0
      const float gr = gp[o], gz = gp[512+o], gn = gp[1024+o];

      u64t d[32];
      poll32(ring0 + (size_t)((t-1)&15)*256 + 32*j, (unsigned)(t+1), d, &bd);
      float a0,a1,a2; dot96t(w,d,a0,a1,a2);
      a0 = qsum8(a0); a1 = qsum8(a1); a2 = qsum8(a2);

      const float r = sigmoidf_(gr + a0 + br);
      const float z = sigmoidf_(gz + a1 + bz);
      const float n = tanhf_(gn + r*(a2 + bn));
      const float h = (1.f - z)*n + z*hreg;
      hreg = h;
      const float hx = __shfl_xor(h, 8, 64);            // h(o^1)
      if ((tid&15)==0)
        st_a64(ring0 + (size_t)(t&15)*256 + (o>>1),
               ((u64t)(unsigned)(t+2)<<32) | pack2h(h, hx));
      if (t==TS-1 && (tid&7)==0) hnext[o] = h;
    }
  } else if (wg < 16){
    // ===================== layer 1 =====================
    const int q = wg-8;
    const int o = q*64 + (tid>>3);
    const int j = tid&7;
    h2 w[96];
    loadseg(&w[0],  Whh1 + (size_t)o*512         + 64*j);
    loadseg(&w[32], Whh1 + (size_t)(512+o)*512   + 64*j);
    loadseg(&w[64], Whh1 + (size_t)(1024+o)*512  + 64*j);
    const float br=bhh1[o], bz=bhh1[512+o], bn=bhh1[1024+o];
    float hreg = hprev[512+o];
    if ((tid&15)==0)
      st_a64(ring1 + 15*256 + (o>>1), ((u64t)1<<32) | pack2h(hprev[512+o], hprev[512+o+1]));

    for (int s=0; s<TS; ++s){
      if ((s&3)==0){
        if (lane==0) st_u32(progS + wg*8 + wv, (unsigned)s);
        if (s>=16){
          const int need = s-12;
          for(;;){
            int v = (int)ld_u32(progS + 64 + lane);     // L1 rows 8..15
            if (wave_min(v) >= need) break;
            if (--bd<0) break;
          }
        }
      }
      // gi1(s): 3 tagged words (issued early, checked after the recurrence dot)
      const u64t* gb = gir + (size_t)(s&15)*768;
      const int wo = o>>1;
      const unsigned wantg = (unsigned)(s+2);
      u64t G0 = ld_a64(gb+wo), G1 = ld_a64(gb+256+wo), G2 = ld_a64(gb+512+wo);

      u64t d[32];
      poll32(ring1 + (size_t)((s-1)&15)*256 + 32*j, (unsigned)(s+1), d, &bd);
      float a0,a1,a2; dot96t(w,d,a0,a1,a2);
      a0 = qsum8(a0); a1 = qsum8(a1); a2 = qsum8(a2);

      for(;;){
        bool ok = (tg(G0)==wantg) && (tg(G1)==wantg) && (tg(G2)==wantg);
        if (ok) break;
        if (--bd<0) break;
        if (tg(G0)!=wantg) G0 = ld_a64(gb+wo);
        if (tg(G1)!=wantg) G1 = ld_a64(gb+256+wo);
        if (tg(G2)!=wantg) G2 = ld_a64(gb+512+wo);
      }
      const int half = o&1;
      h2 v0 = u2h2((uint32_t)G0), v1 = u2h2((uint32_t)G1), v2 = u2h2((uint32_t)G2);
      const float gr = half ? (float)v0[1] : (float)v0[0];   // includes bih1
      const float gz = half ? (float)v1[1] : (float)v1[0];
      const float gn = half ? (float)v2[1] : (float)v2[0];

      const float r = sigmoidf_(gr + a0 + br);
      const float z = sigmoidf_(gz + a1 + bz);
      const float n = tanhf_(gn + r*(a2 + bn));
      const float h = (1.f - z)*n + z*hreg;
      hreg = h;
      if ((tid&7)==0) H1[(size_t)s*512 + o] = h;
      const float hx = __shfl_xor(h, 8, 64);
      if ((tid&15)==0)
        st_a64(ring1 + (size_t)(s&15)*256 + (o>>1),
               ((u64t)(unsigned)(s+2)<<32) | pack2h(h, hx));
      if ((s&15)==15 && lane==0)
        __hip_atomic_store(progH + q*8 + wv, (unsigned)(s+1),
                           __ATOMIC_RELEASE, __HIP_MEMORY_SCOPE_AGENT);
      if (s==TS-1 && (tid&7)==0) hnext[512+o] = h;
    }
    if (lane==0)
      __hip_atomic_store(progH + q*8 + wv, (unsigned)TS,
                         __ATOMIC_RELEASE, __HIP_MEMORY_SCOPE_AGENT);
  } else if (wg < 24){
    // ===================== gi1 helpers =====================
    const int hh = wg-16;
    const int o = hh*64 + (tid>>3);
    const int j = tid&7;
    h2 w[96];
    loadseg(&w[0],  Wih1 + (size_t)o*512         + 64*j);
    loadseg(&w[32], Wih1 + (size_t)(512+o)*512   + 64*j);
    loadseg(&w[64], Wih1 + (size_t)(1024+o)*512  + 64*j);
    const float b0=bih1[o], b1=bih1[512+o], b2=bih1[1024+o];

    for (int s=0; s<TS; ++s){
      if ((s&3)==0){
        if (lane==0) st_u32(progS + wg*8 + wv, (unsigned)s);
        if (s>=16){
          const int need = s-12;
          for(;;){
            int v = (int)ld_u32(progS + 64 + lane);     // gir consumers: L1 rows
            if (wave_min(v) >= need) break;
            if (--bd<0) break;
          }
        }
      }
      u64t d[32];
      poll32(ring0 + (size_t)(s&15)*256 + 32*j, (unsigned)(s+2), d, &bd);
      float a0,a1,a2; dot96t(w,d,a0,a1,a2);
      a0 = qsum8(a0)+b0; a1 = qsum8(a1)+b1; a2 = qsum8(a2)+b2;
      const float x0=__shfl_xor(a0,8,64), x1=__shfl_xor(a1,8,64), x2=__shfl_xor(a2,8,64);
      if ((tid&15)==0){
        u64t* gb = gir + (size_t)(s&15)*768;
        const u64t tag = (u64t)(unsigned)(s+2)<<32;
        st_a64(gb + (o>>1),       tag | pack2h(a0,x0));
        st_a64(gb + 256 + (o>>1), tag | pack2h(a1,x1));
        st_a64(gb + 512 + (o>>1), tag | pack2h(a2,x2));
      }
    }
  } else {
    // ===================== FC GEMM workers =====================
    float* As = lds;            // [32][132]
    float* Bs = lds + 32*132;   // [32][68]
    int*   comm = (int*)&lds[6404];
    const int tm = tid>>4, tn = tid&15;
    const int m0 = tid>>2, kk0a = (tid&3)*8;
    const int n0 = tid>>3, kk0b = (tid&7)*4;
    long fcbd = 1L<<24;
    for(;;){
      if (tid==0) comm[0] = (int)atomicAdd(ticket, 1u);
      __syncthreads();
      const int tau = comm[0];
      __syncthreads();
      if (tau >= 2048) break;
      const int bm = tau>>6, bn = tau&63;
      if (tid==0){
        const unsigned need = (unsigned)(bm*128 + 128);
        for(;;){
          unsigned mn = 0xffffffffu;
          for (int k2=0;k2<64;++k2){ unsigned v = ld_u32(progH+k2); mn = v<mn?v:mn; }
          if (mn >= need) break;
          __builtin_amdgcn_s_sleep(16);
          if (--fcbd < 0) break;
        }
      }
      __syncthreads();
      __builtin_amdgcn_fence(__ATOMIC_ACQUIRE, "agent");   // invalidate stale H1 lines

      const float* A = H1  + (size_t)bm*128*512;
      const float* B = Wfc + (size_t)bn*64*512;
      float acc[4][4] = {};
      for (int k0=0; k0<512; k0+=32){
        #pragma unroll
        for (int jj=0;jj<8;++jj) As[(kk0a+jj)*132 + m0] = A[(size_t)m0*512 + k0+kk0a+jj];
        #pragma unroll
        for (int jj=0;jj<4;++jj) Bs[(kk0b+jj)*68  + n0] = B[(size_t)n0*512 + k0+kk0b+jj];
        __syncthreads();
        #pragma unroll
        for (int kk=0;kk<32;++kk){
          const float4 av = *(const float4*)&As[kk*132 + tm*4];
          const float4 bv = *(const float4*)&Bs[kk*68  + tn*4];
          acc[0][0]=fmaf(av.x,bv.x,acc[0][0]); acc[0][1]=fmaf(av.x,bv.y,acc[0][1]);
          acc[0][2]=fmaf(av.x,bv.z,acc[0][2]); acc[0][3]=fmaf(av.x,bv.w,acc[0][3]);
          acc[1][0]=fmaf(av.y,bv.x,acc[1][0]); acc[1][1]=fmaf(av.y,bv.y,acc[1][1]);
          acc[1][2]=fmaf(av.y,bv.z,acc[1][2]); acc[1][3]=fmaf(av.y,bv.w,acc[1][3]);
          acc[2][0]=fmaf(av.z,bv.x,acc[2][0]); acc[2][1]=fmaf(av.z,bv.y,acc[2][1]);
          acc[2][2]=fmaf(av.z,bv.z,acc[2][2]); acc[2][3]=fmaf(av.z,bv.w,acc[2][3]);
          acc[3][0]=fmaf(av.w,bv.x,acc[3][0]); acc[3][1]=fmaf(av.w,bv.y,acc[3][1]);
          acc[3][2]=fmaf(av.w,bv.z,acc[3][2]); acc[3][3]=fmaf(av.w,bv.w,acc[3][3]);
        }
        __syncthreads();
      }
      const int cc0 = bn*64 + tn*4;
      const int mk0 = mask[cc0], mk1 = mask[cc0+1], mk2 = mask[cc0+2], mk3 = mask[cc0+3];
      const float b0 = bfc[cc0], b1 = bfc[cc0+1], b2 = bfc[cc0+2], b3 = bfc[cc0+3];
      #pragma unroll
      for (int i=0;i<4;++i){
        const int mm = bm*128 + tm*4 + i;
        float4 v;
        v.x = fmaxf(acc[i][0]+b0, 0.f); if (mk0==0) v.x = NEG_VAL;
        v.y = fmaxf(acc[i][1]+b1, 0.f); if (mk1==0) v.y = NEG_VAL;
        v.z = fmaxf(acc[i][2]+b2, 0.f); if (mk2==0) v.z = NEG_VAL;
        v.w = fmaxf(acc[i][3]+b3, 0.f); if (mk3==0) v.w = NEG_VAL;
        *(float4*)&out[(size_t)mm*4096 + cc0] = v;
      }
    }
  }
}

// ---------------- gi0 = state[:,1:] @ Wih0^T + bih0 (f32) ----------------
__global__ __launch_bounds__(256) void gemm_gi0(
    const float* __restrict__ A, int lda,
    const float* __restrict__ B, int ldb,
    float* __restrict__ C, int ldc,
    const float* __restrict__ bias, int K)
{
  __shared__ __align__(16) float As[32][68];
  __shared__ __align__(16) float Bs[32][68];
  const int bm = blockIdx.y*64, bn = blockIdx.x*64;
  const int tid = threadIdx.x;
  const int tm = tid>>4, tn = tid&15;
  float acc[4][4] = {};
  const int m0 = tid>>2, kk0 = (tid&3)*8;
  for (int k0=0; k0<K; k0+=32){
    #pragma unroll
    for (int j=0;j<8;++j) As[kk0+j][m0] = A[(size_t)(bm+m0)*lda + k0+kk0+j];
    #pragma unroll
    for (int j=0;j<8;++j) Bs[kk0+j][m0] = B[(size_t)(bn+m0)*ldb + k0+kk0+j];
    __syncthreads();
    #pragma unroll
    for (int kk=0;kk<32;++kk){
      const float4 av = *(const float4*)&As[kk][tm*4];
      const float4 bv = *(const float4*)&Bs[kk][tn*4];
      acc[0][0]=fmaf(av.x,bv.x,acc[0][0]); acc[0][1]=fmaf(av.x,bv.y,acc[0][1]);
      acc[0][2]=fmaf(av.x,bv.z,acc[0][2]); acc[0][3]=fmaf(av.x,bv.w,acc[0][3]);
      acc[1][0]=fmaf(av.y,bv.x,acc[1][0]); acc[1][1]=fmaf(av.y,bv.y,acc[1][1]);
      acc[1][2]=fmaf(av.y,bv.z,acc[1][2]); acc[1][3]=fmaf(av.y,bv.w,acc[1][3]);
      acc[2][0]=fmaf(av.z,bv.x,acc[2][0]); acc[2][1]=fmaf(av.z,bv.y,acc[2][1]);
      acc[2][2]=fmaf(av.z,bv.z,acc[2][2]); acc[2][3]=fmaf(av.z,bv.w,acc[2][3]);
      acc[3][0]=fmaf(av.w,bv.x,acc[3][0]); acc[3][1]=fmaf(av.w,bv.y,acc[3][1]);
      acc[3][2]=fmaf(av.w,bv.z,acc[3][2]); acc[3][3]=fmaf(av.w,bv.w,acc[3][3]);
    }
    __syncthreads();
  }
  #pragma unroll
  for (int i=0;i<4;++i){
    #pragma unroll
    for (int j=0;j<4;++j){
      const int mm = bm + tm*4 + i, cc = bn + tn*4 + j;
      C[(size_t)mm*ldc + cc] = acc[i][j] + bias[cc];
    }
  }
}

// ---------------- launch ----------------
extern "C" void kernel_launch(void* const* d_in, const int* in_sizes, int n_in,
                              void* d_out, int out_size, void* d_ws, size_t ws_size,
                              hipStream_t stream)
{
  const float* state = (const float*)d_in[0];   // (4096, 129)
  const float* hprev = (const float*)d_in[1];   // (2, 512)
  const int*   mask  = (const int*)d_in[2];     // (64, 64)
  const float* Wih0  = (const float*)d_in[3];   // (1536, 128)
  const float* Whh0  = (const float*)d_in[4];   // (1536, 512)
  const float* bih0  = (const float*)d_in[5];
  const float* bhh0  = (const float*)d_in[6];
  const float* Wih1  = (const float*)d_in[7];   // (1536, 512)
  const float* Whh1  = (const float*)d_in[8];   // (1536, 512)
  const float* bih1  = (const float*)d_in[9];
  const float* bhh1  = (const float*)d_in[10];
  const float* Wfc   = (const float*)d_in[11];  // (4096, 512)
  const float* bfc   = (const float*)d_in[12];

  if (ws_size < WS_NEED) return;

  float* out = (float*)d_out;
  char*  ws  = (char*)d_ws;
  float* gi0 = (float*)(ws + GI0_OFF);
  float* H1  = (float*)(ws + H1_OFF);
  u64t*  ring0 = (u64t*)(ws + R0_OFF);
  u64t*  ring1 = (u64t*)(ws + R1_OFF);
  u64t*  gir   = (u64t*)(ws + GIR_OFF);
  unsigned* progS = (unsigned*)(ws + PROGS_OFF);
  unsigned* progH = (unsigned*)(ws + PROGH_OFF);
  unsigned* tick  = (unsigned*)(ws + TICK_OFF);

  // clear rings/tags/progress/ticket each call (graph replays reuse ws; tag 0 never valid)
  (void)hipMemsetAsync(ws + R0_OFF, 0, (size_t)(WS_NEED - R0_OFF), stream);

  // gi0 precompute: M=4096, N=1536, K=128
  {
    dim3 grid(1536/64, 4096/64);
    gemm_gi0<<<grid, 256, 0, stream>>>(state+1, 129, Wih0, 128, gi0, 1536, bih0, 128);
  }

  actor_fused<<<256, 512, 0, stream>>>(
      hprev, mask, Whh0, bhh0, Wih1, Whh1, bih1, bhh1, Wfc, bfc,
      gi0, H1, ring0, ring1, gir, progS, progH, tick,
      out, out + (size_t)4096*4096);
}

// Round 7
// 15583.127 us; speedup vs baseline: 6.3925x; 6.3925x over previous
//
#include <hip/hip_runtime.h>
#include <stdint.h>

#define TS 4096
#define NEG_VAL -1000000000.0f

typedef _Float16 h2 __attribute__((ext_vector_type(2)));
typedef unsigned long long u64t;

// ---------------- workspace layout (bytes) ----------------
#define GI0_OFF   ((size_t)0)                       // 4096*1536*4 = 25165824
#define H1_OFF    ((size_t)25165824)                // 4096*512*4  = 8388608
#define MB0L0_OFF ((size_t)33554432)                // 8 cons * 16 slots * 256 w * 8B = 262144
#define MB0L1_OFF ((size_t)33816576)                // 16*16*256*8 = 524288
#define MB1L1_OFF ((size_t)34340864)                // 16*16*256*8 = 524288
#define PROGS_OFF ((size_t)34865152)                // 24 * 64B lines
#define PROGH_OFF ((size_t)34867200)                // 128 u32
#define TICK_OFF  ((size_t)34867712)
#define WS_NEED   ((size_t)34867776)

// ---------------- helpers ----------------
static __device__ __forceinline__ u64t ld_a64(const u64t* p){
  return __hip_atomic_load(p, __ATOMIC_RELAXED, __HIP_MEMORY_SCOPE_AGENT);
}
static __device__ __forceinline__ void st_a64(u64t* p, u64t v){
  __hip_atomic_store(p, v, __ATOMIC_RELAXED, __HIP_MEMORY_SCOPE_AGENT);
}
static __device__ __forceinline__ unsigned ld_u32(const unsigned* p){
  return __hip_atomic_load(p, __ATOMIC_RELAXED, __HIP_MEMORY_SCOPE_AGENT);
}
static __device__ __forceinline__ void st_u32(unsigned* p, unsigned v){
  __hip_atomic_store(p, v, __ATOMIC_RELAXED, __HIP_MEMORY_SCOPE_AGENT);
}
static __device__ __forceinline__ float sigmoidf_(float x){
  return 1.0f / (1.0f + __expf(-x));
}
static __device__ __forceinline__ float tanhf_(float x){
  float ax = fabsf(x);
  float e  = __expf(-2.0f*ax);
  float t  = (1.0f - e) / (1.0f + e);
  return copysignf(t, x);
}
static __device__ __forceinline__ uint32_t pack2h(float a, float b){
  _Float16 ha = (_Float16)a, hb = (_Float16)b;
  unsigned short ua = __builtin_bit_cast(unsigned short, ha);
  unsigned short ub = __builtin_bit_cast(unsigned short, hb);
  return (uint32_t)ua | ((uint32_t)ub << 16);
}
static __device__ __forceinline__ h2 u2h2(uint32_t u){ return __builtin_bit_cast(h2, u); }
static __device__ __forceinline__ unsigned tg(u64t v){ return (unsigned)(v>>32); }

template<int CTRL>
static __device__ __forceinline__ float dppx(float x){
  return __int_as_float(__builtin_amdgcn_update_dpp(0, __float_as_int(x), CTRL, 0xF, 0xF, true));
}
static __device__ __forceinline__ float qsum8(float x){
  x += dppx<0xB1>(x);
  x += dppx<0x4E>(x);
  x += __shfl_xor(x, 4, 64);
  return x;
}
static __device__ __forceinline__ float qsum16(float x){
  x += dppx<0xB1>(x);
  x += dppx<0x4E>(x);
  x += __shfl_xor(x, 4, 64);
  x += __shfl_xor(x, 8, 64);
  return x;
}
static __device__ __forceinline__ int wave_min(int v){
  #pragma unroll
  for (int off=32; off; off>>=1){ int o = __shfl_xor(v, off, 64); v = o<v?o:v; }
  return v;
}

#if __has_builtin(__builtin_amdgcn_fdot2)
#define FDOT2(a,b,c) __builtin_amdgcn_fdot2((a),(b),(c),false)
#else
static __device__ __forceinline__ float FDOT2(h2 a, h2 b, float c){
  return c + (float)a[0]*(float)b[0] + (float)a[1]*(float)b[1];
}
#endif

// each lane polls 4 consecutive self-tagged words; wave-wide ready check.
static __device__ __forceinline__ void poll4(const u64t* base, unsigned want,
                                             uint32_t (&v)[4], long* bd, bool* fail){
  u64t p0=ld_a64(base), p1=ld_a64(base+1), p2=ld_a64(base+2), p3=ld_a64(base+3);
  for(;;){
    bool ok = (tg(p0)==want)&&(tg(p1)==want)&&(tg(p2)==want)&&(tg(p3)==want);
    if (__all(ok)) break;
    if (--(*bd) < 0){ *fail = true; break; }
    __builtin_amdgcn_s_sleep(1);
    if (tg(p0)!=want) p0=ld_a64(base);
    if (tg(p1)!=want) p1=ld_a64(base+1);
    if (tg(p2)!=want) p2=ld_a64(base+2);
    if (tg(p3)!=want) p3=ld_a64(base+3);
  }
  v[0]=(uint32_t)p0; v[1]=(uint32_t)p1; v[2]=(uint32_t)p2; v[3]=(uint32_t)p3;
}
// f32 row segment -> f16 regs: 32 h2 (64 cols)
static __device__ __forceinline__ void seg32(h2* dst, const float* src){
  const float4* p = (const float4*)src;
  #pragma unroll
  for (int k=0;k<16;++k){
    float4 v = p[k];
    dst[2*k]   = h2{(_Float16)v.x,(_Float16)v.y};
    dst[2*k+1] = h2{(_Float16)v.z,(_Float16)v.w};
  }
}
// 16 h2 (32 cols)
static __device__ __forceinline__ void seg16(h2* dst, const float* src){
  const float4* p = (const float4*)src;
  #pragma unroll
  for (int k=0;k<8;++k){
    float4 v = p[k];
    dst[2*k]   = h2{(_Float16)v.x,(_Float16)v.y};
    dst[2*k+1] = h2{(_Float16)v.z,(_Float16)v.w};
  }
}

// ================= fused kernel: 256 WGs x 512 thr =================
// WG 0..7  : layer0 (Whh0; 64 out/WG; 8 lanes/out; w[96] VGPR; private mailbox MB0L0[wg])
// WG 8..23 : layer1 (Whh1+Wih1 folded; 32 out/WG; 16 lanes/out; w[96] VGPR)
// WG 24..255: FC GEMM workers (128x64 tiles, ticketed, gated on per-wave progH)
// word = tag(step+2)<<32 | 2xf16 ; seeds: h(-1) at slot 15 with tag 1.
__global__ __launch_bounds__(512,1) void actor_fused(
    const float* __restrict__ hprev,
    const int*   __restrict__ mask,
    const float* __restrict__ Whh0,
    const float* __restrict__ bhh0,
    const float* __restrict__ Wih1,
    const float* __restrict__ Whh1,
    const float* __restrict__ bih1,
    const float* __restrict__ bhh1,
    const float* __restrict__ Wfc,
    const float* __restrict__ bfc,
    const float* __restrict__ gi0,
    float* __restrict__ H1,
    u64t* mb0l0, u64t* mb0l1, u64t* mb1l1,
    unsigned* progS, unsigned* progH, unsigned* ticket,
    float* __restrict__ out, float* __restrict__ hnext)
{
  const int wg   = blockIdx.x;
  const int tid  = threadIdx.x;
  const int wv   = tid >> 6;
  const int lane = tid & 63;
  __shared__ __align__(16) float lds[6464];
  volatile int* fcp = (volatile int*)lds;
  long bd = 1L<<22;
  bool fail = false;

  if (wg < 24){
    // ---- common flow-control lambda-ish macro via code dup below ----
    if (wg < 8){
      // ===================== layer 0 =====================
      const int j = lane & 7;
      const int o = wg*64 + (tid>>3);
      h2 w[96];
      seg32(&w[0],  Whh0 + (size_t)o*512         + 64*j);
      seg32(&w[32], Whh0 + (size_t)(512+o)*512   + 64*j);
      seg32(&w[64], Whh0 + (size_t)(1024+o)*512  + 64*j);
      const float br=bhh0[o], bz=bhh0[512+o], bn=bhh0[1024+o];
      float hreg = hprev[o];
      if ((tid&1)==0)
        st_a64(mb0l0 + ((size_t)wg*16 + 15)*256 + (tid>>1),
               ((u64t)1<<32) | pack2h(hprev[tid], hprev[tid+1]));
      if (tid==0) fcp[0] = 0;
      __syncthreads();

      for (int t=0; t<TS; ++t){
        if ((t&3)==0){
          if (wv==0 && lane==0) st_u32(progS + wg*16, (unsigned)(t-1));
          if (t>=16){
            const int need = t-11;
            if (wv==0){
              int v = (lane<24)? (int)ld_u32(progS + lane*16) : 0x7fffffff;
              int mn = wave_min(v);
              while (mn < need){
                if (--bd<0){ fail=true; break; }
                __builtin_amdgcn_s_sleep(4);
                v = (lane<24)? (int)ld_u32(progS + lane*16) : 0x7fffffff;
                mn = wave_min(v);
              }
              if (lane==0) fcp[0] = t;
            } else {
              while (fcp[0] < t){ if (--bd<0){ fail=true; break; } __builtin_amdgcn_s_sleep(4); }
            }
            if (fail) break;
          }
        }
        const float* gp = gi0 + (size_t)t*1536;       // includes bih0
        const float gr = gp[o], gz = gp[512+o], gn = gp[1024+o];

        uint32_t v[4];
        poll4(mb0l0 + ((size_t)wg*16 + ((t-1)&15))*256 + 4*lane, (unsigned)(t+1), v, &bd, &fail);
        if (fail) break;
        // redistribute: lane needs words 32j..32j+31; word 32j+4i+k at lane 8j+i reg k
        uint32_t hw[32];
        const int sj = 8*j;
        #pragma unroll
        for (int i=0;i<8;++i){
          const int src = sj + i;
          hw[4*i+0] = (uint32_t)__shfl((int)v[0], src, 64);
          hw[4*i+1] = (uint32_t)__shfl((int)v[1], src, 64);
          hw[4*i+2] = (uint32_t)__shfl((int)v[2], src, 64);
          hw[4*i+3] = (uint32_t)__shfl((int)v[3], src, 64);
        }
        float a0=0.f, a1=0.f, a2=0.f;
        #pragma unroll
        for (int m=0;m<32;++m){
          h2 hv = u2h2(hw[m]);
          a0 = FDOT2(w[m],    hv, a0);
          a1 = FDOT2(w[32+m], hv, a1);
          a2 = FDOT2(w[64+m], hv, a2);
        }
        a0 = qsum8(a0); a1 = qsum8(a1); a2 = qsum8(a2);

        const float r = sigmoidf_(gr + a0 + br);
        const float z = sigmoidf_(gz + a1 + bz);
        const float n = tanhf_(gn + r*(a2 + bn));
        const float h = (1.f - z)*n + z*hreg;
        hreg = h;

        const float hx = __shfl_xor(h, 8, 64);
        const uint32_t wval = (o&1)? pack2h(hx,h) : pack2h(h,hx);
        const u64t word = ((u64t)(unsigned)(t+2)<<32) | wval;
        const int wi = wg*32 + (tid>>4);
        const int d = (tid&7) | (((tid>>3)&1)<<3);
        const int slot = t&15;
        if (d<8){
          st_a64(mb0l0 + ((size_t)d*16 + slot)*256 + wi, word);
          st_a64(mb0l1 + ((size_t)(8+d)*16 + slot)*256 + wi, word);
        } else {
          st_a64(mb0l1 + ((size_t)(d-8)*16 + slot)*256 + wi, word);
        }
        if (t==TS-1 && j==0) hnext[o] = h;
      }
    } else {
      // ===================== layer 1 (gi1 folded in) =====================
      const int q = wg-8;
      const int j = lane & 15;
      const int ol = q*32 + (tid>>4);
      h2 w[96];
      seg16(&w[0],  Whh1 + (size_t)ol*512         + 32*j);
      seg16(&w[16], Whh1 + (size_t)(512+ol)*512   + 32*j);
      seg16(&w[32], Whh1 + (size_t)(1024+ol)*512  + 32*j);
      seg16(&w[48], Wih1 + (size_t)ol*512         + 32*j);
      seg16(&w[64], Wih1 + (size_t)(512+ol)*512   + 32*j);
      seg16(&w[80], Wih1 + (size_t)(1024+ol)*512  + 32*j);
      const float brc = bih1[ol]      + bhh1[ol];
      const float bzc = bih1[512+ol]  + bhh1[512+ol];
      const float bin = bih1[1024+ol];
      const float bhn = bhh1[1024+ol];
      float hreg = hprev[512+ol];
      if ((tid&1)==0)
        st_a64(mb1l1 + ((size_t)q*16 + 15)*256 + (tid>>1),
               ((u64t)1<<32) | pack2h(hprev[512+tid], hprev[512+tid+1]));
      if (tid==0) fcp[0] = 0;
      __syncthreads();

      for (int s=0; s<TS; ++s){
        if ((s&3)==0){
          if (wv==0 && lane==0) st_u32(progS + wg*16, (unsigned)(s-1));
          if (s>=16){
            const int need = s-11;
            if (wv==0){
              int v = (lane<24)? (int)ld_u32(progS + lane*16) : 0x7fffffff;
              int mn = wave_min(v);
              while (mn < need){
                if (--bd<0){ fail=true; break; }
                __builtin_amdgcn_s_sleep(4);
                v = (lane<24)? (int)ld_u32(progS + lane*16) : 0x7fffffff;
                mn = wave_min(v);
              }
              if (lane==0) fcp[0] = s;
            } else {
              while (fcp[0] < s){ if (--bd<0){ fail=true; break; } __builtin_amdgcn_s_sleep(4); }
            }
            if (fail) break;
          }
        }
        uint32_t va[4], vb[4];
        poll4(mb1l1 + ((size_t)q*16 + ((s-1)&15))*256 + 4*lane, (unsigned)(s+1), va, &bd, &fail);
        if (fail) break;
        poll4(mb0l1 + ((size_t)q*16 + (s&15))*256 + 4*lane, (unsigned)(s+2), vb, &bd, &fail);
        if (fail) break;
        // redistribute: lane needs h1/h0 words 16j..16j+15; word 16j+4r+k at lane 4j+r reg k
        uint32_t h1w[16], h0w[16];
        const int s4 = 4*j;
        #pragma unroll
        for (int rr=0;rr<4;++rr){
          const int src = s4 + rr;
          h1w[4*rr+0]=(uint32_t)__shfl((int)va[0],src,64);
          h1w[4*rr+1]=(uint32_t)__shfl((int)va[1],src,64);
          h1w[4*rr+2]=(uint32_t)__shfl((int)va[2],src,64);
          h1w[4*rr+3]=(uint32_t)__shfl((int)va[3],src,64);
          h0w[4*rr+0]=(uint32_t)__shfl((int)vb[0],src,64);
          h0w[4*rr+1]=(uint32_t)__shfl((int)vb[1],src,64);
          h0w[4*rr+2]=(uint32_t)__shfl((int)vb[2],src,64);
          h0w[4*rr+3]=(uint32_t)__shfl((int)vb[3],src,64);
        }
        float a0=0.f,a1=0.f,a2=0.f,b0=0.f,b1=0.f,b2=0.f;
        #pragma unroll
        for (int m=0;m<16;++m){
          h2 hv1 = u2h2(h1w[m]);
          h2 hv0 = u2h2(h0w[m]);
          a0 = FDOT2(w[m],    hv1, a0);
          a1 = FDOT2(w[16+m], hv1, a1);
          a2 = FDOT2(w[32+m], hv1, a2);
          b0 = FDOT2(w[48+m], hv0, b0);
          b1 = FDOT2(w[64+m], hv0, b1);
          b2 = FDOT2(w[80+m], hv0, b2);
        }
        const float sr  = qsum16(a0+b0);
        const float sz  = qsum16(a1+b1);
        const float shn = qsum16(a2);        // hh part of n
        const float sin_= qsum16(b2);        // ih part of n

        const float r = sigmoidf_(sr + brc);
        const float z = sigmoidf_(sz + bzc);
        const float n = tanhf_((sin_ + bin) + r*(shn + bhn));
        const float h = (1.f - z)*n + z*hreg;
        hreg = h;

        if (j==0) H1[(size_t)s*512 + ol] = h;
        const float hx = __shfl_xor(h, 16, 64);
        const uint32_t wval = (ol&1)? pack2h(hx,h) : pack2h(h,hx);
        const u64t word = ((u64t)(unsigned)(s+2)<<32) | wval;
        const int wi = q*16 + (tid>>5);
        const int d = (tid&15) | (((tid>>4)&1)<<4);
        if (d<16)
          st_a64(mb1l1 + ((size_t)d*16 + (s&15))*256 + wi, word);
        if ((s&15)==15 && lane==0)
          __hip_atomic_store(progH + q*8 + wv, (unsigned)(s+1),
                             __ATOMIC_RELEASE, __HIP_MEMORY_SCOPE_AGENT);
        if (s==TS-1 && j==0) hnext[512+ol] = h;
      }
      if (lane==0)
        __hip_atomic_store(progH + q*8 + wv, (unsigned)TS,
                           __ATOMIC_RELEASE, __HIP_MEMORY_SCOPE_AGENT);
    }
  } else {
    // ===================== FC GEMM workers =====================
    float* As = lds;            // [32][132]
    float* Bs = lds + 32*132;   // [32][68]
    int*   comm = (int*)&lds[6460];
    const int tm = tid>>4, tn = tid&15;
    const int m0 = tid>>2, kk0a = (tid&3)*8;
    const int n0 = tid>>3, kk0b = (tid&7)*4;
    long fcbd = 1L<<24;
    for(;;){
      if (tid==0) comm[0] = (int)atomicAdd(ticket, 1u);
      __syncthreads();
      const int tau = comm[0];
      __syncthreads();
      if (tau >= 2048) break;
      const int bm = tau>>6, bn = tau&63;
      if (tid==0){
        const unsigned need = (unsigned)(bm*128 + 128);
        for(;;){
          unsigned mn = 0xffffffffu;
          for (int k2=0;k2<128;++k2){ unsigned v = ld_u32(progH+k2); mn = v<mn?v:mn; }
          if (mn >= need) break;
          __builtin_amdgcn_s_sleep(16);
          if (--fcbd < 0) break;
        }
      }
      __syncthreads();
      __builtin_amdgcn_fence(__ATOMIC_ACQUIRE, "agent");

      const float* A = H1  + (size_t)bm*128*512;
      const float* B = Wfc + (size_t)bn*64*512;
      float acc[4][4] = {};
      for (int k0=0; k0<512; k0+=32){
        #pragma unroll
        for (int jj=0;jj<8;++jj) As[(kk0a+jj)*132 + m0] = A[(size_t)m0*512 + k0+kk0a+jj];
        #pragma unroll
        for (int jj=0;jj<4;++jj) Bs[(kk0b+jj)*68  + n0] = B[(size_t)n0*512 + k0+kk0b+jj];
        __syncthreads();
        #pragma unroll
        for (int kk=0;kk<32;++kk){
          const float4 av = *(const float4*)&As[kk*132 + tm*4];
          const float4 bv = *(const float4*)&Bs[kk*68  + tn*4];
          acc[0][0]=fmaf(av.x,bv.x,acc[0][0]); acc[0][1]=fmaf(av.x,bv.y,acc[0][1]);
          acc[0][2]=fmaf(av.x,bv.z,acc[0][2]); acc[0][3]=fmaf(av.x,bv.w,acc[0][3]);
          acc[1][0]=fmaf(av.y,bv.x,acc[1][0]); acc[1][1]=fmaf(av.y,bv.y,acc[1][1]);
          acc[1][2]=fmaf(av.y,bv.z,acc[1][2]); acc[1][3]=fmaf(av.y,bv.w,acc[1][3]);
          acc[2][0]=fmaf(av.z,bv.x,acc[2][0]); acc[2][1]=fmaf(av.z,bv.y,acc[2][1]);
          acc[2][2]=fmaf(av.z,bv.z,acc[2][2]); acc[2][3]=fmaf(av.z,bv.w,acc[2][3]);
          acc[3][0]=fmaf(av.w,bv.x,acc[3][0]); acc[3][1]=fmaf(av.w,bv.y,acc[3][1]);
          acc[3][2]=fmaf(av.w,bv.z,acc[3][2]); acc[3][3]=fmaf(av.w,bv.w,acc[3][3]);
        }
        __syncthreads();
      }
      const int cc0 = bn*64 + tn*4;
      const int mk0 = mask[cc0], mk1 = mask[cc0+1], mk2 = mask[cc0+2], mk3 = mask[cc0+3];
      const float b0 = bfc[cc0], b1 = bfc[cc0+1], b2 = bfc[cc0+2], b3 = bfc[cc0+3];
      #pragma unroll
      for (int i=0;i<4;++i){
        const int mm = bm*128 + tm*4 + i;
        float4 vv;
        vv.x = fmaxf(acc[i][0]+b0, 0.f); if (mk0==0) vv.x = NEG_VAL;
        vv.y = fmaxf(acc[i][1]+b1, 0.f); if (mk1==0) vv.y = NEG_VAL;
        vv.z = fmaxf(acc[i][2]+b2, 0.f); if (mk2==0) vv.z = NEG_VAL;
        vv.w = fmaxf(acc[i][3]+b3, 0.f); if (mk3==0) vv.w = NEG_VAL;
        *(float4*)&out[(size_t)mm*4096 + cc0] = vv;
      }
    }
  }
}

// ---------------- gi0 = state[:,1:] @ Wih0^T + bih0 (f32) ----------------
__global__ __launch_bounds__(256) void gemm_gi0(
    const float* __restrict__ A, int lda,
    const float* __restrict__ B, int ldb,
    float* __restrict__ C, int ldc,
    const float* __restrict__ bias, int K)
{
  __shared__ __align__(16) float As[32][68];
  __shared__ __align__(16) float Bs[32][68];
  const int bm = blockIdx.y*64, bn = blockIdx.x*64;
  const int tid = threadIdx.x;
  const int tm = tid>>4, tn = tid&15;
  float acc[4][4] = {};
  const int m0 = tid>>2, kk0 = (tid&3)*8;
  for (int k0=0; k0<K; k0+=32){
    #pragma unroll
    for (int j=0;j<8;++j) As[kk0+j][m0] = A[(size_t)(bm+m0)*lda + k0+kk0+j];
    #pragma unroll
    for (int j=0;j<8;++j) Bs[kk0+j][m0] = B[(size_t)(bn+m0)*ldb + k0+kk0+j];
    __syncthreads();
    #pragma unroll
    for (int kk=0;kk<32;++kk){
      const float4 av = *(const float4*)&As[kk][tm*4];
      const float4 bv = *(const float4*)&Bs[kk][tn*4];
      acc[0][0]=fmaf(av.x,bv.x,acc[0][0]); acc[0][1]=fmaf(av.x,bv.y,acc[0][1]);
      acc[0][2]=fmaf(av.x,bv.z,acc[0][2]); acc[0][3]=fmaf(av.x,bv.w,acc[0][3]);
      acc[1][0]=fmaf(av.y,bv.x,acc[1][0]); acc[1][1]=fmaf(av.y,bv.y,acc[1][1]);
      acc[1][2]=fmaf(av.y,bv.z,acc[1][2]); acc[1][3]=fmaf(av.y,bv.w,acc[1][3]);
      acc[2][0]=fmaf(av.z,bv.x,acc[2][0]); acc[2][1]=fmaf(av.z,bv.y,acc[2][1]);
      acc[2][2]=fmaf(av.z,bv.z,acc[2][2]); acc[2][3]=fmaf(av.z,bv.w,acc[2][3]);
      acc[3][0]=fmaf(av.w,bv.x,acc[3][0]); acc[3][1]=fmaf(av.w,bv.y,acc[3][1]);
      acc[3][2]=fmaf(av.w,bv.z,acc[3][2]); acc[3][3]=fmaf(av.w,bv.w,acc[3][3]);
    }
    __syncthreads();
  }
  #pragma unroll
  for (int i=0;i<4;++i){
    #pragma unroll
    for (int j=0;j<4;++j){
      const int mm = bm + tm*4 + i, cc = bn + tn*4 + j;
      C[(size_t)mm*ldc + cc] = acc[i][j] + bias[cc];
    }
  }
}

// ---------------- launch ----------------
extern "C" void kernel_launch(void* const* d_in, const int* in_sizes, int n_in,
                              void* d_out, int out_size, void* d_ws, size_t ws_size,
                              hipStream_t stream)
{
  const float* state = (const float*)d_in[0];   // (4096, 129)
  const float* hprev = (const float*)d_in[1];   // (2, 512)
  const int*   mask  = (const int*)d_in[2];     // (64, 64)
  const float* Wih0  = (const float*)d_in[3];   // (1536, 128)
  const float* Whh0  = (const float*)d_in[4];   // (1536, 512)
  const float* bih0  = (const float*)d_in[5];
  const float* bhh0  = (const float*)d_in[6];
  const float* Wih1  = (const float*)d_in[7];   // (1536, 512)
  const float* Whh1  = (const float*)d_in[8];   // (1536, 512)
  const float* bih1  = (const float*)d_in[9];
  const float* bhh1  = (const float*)d_in[10];
  const float* Wfc   = (const float*)d_in[11];  // (4096, 512)
  const float* bfc   = (const float*)d_in[12];

  if (ws_size < WS_NEED) return;

  float* out = (float*)d_out;
  char*  ws  = (char*)d_ws;
  float* gi0 = (float*)(ws + GI0_OFF);
  float* H1  = (float*)(ws + H1_OFF);
  u64t*  mb0l0 = (u64t*)(ws + MB0L0_OFF);
  u64t*  mb0l1 = (u64t*)(ws + MB0L1_OFF);
  u64t*  mb1l1 = (u64t*)(ws + MB1L1_OFF);
  unsigned* progS = (unsigned*)(ws + PROGS_OFF);
  unsigned* progH = (unsigned*)(ws + PROGH_OFF);
  unsigned* tick  = (unsigned*)(ws + TICK_OFF);

  // clear mailboxes/progress/ticket each call (graph replays reuse ws; tag 0 never valid)
  (void)hipMemsetAsync(ws + MB0L0_OFF, 0, (size_t)(WS_NEED - MB0L0_OFF), stream);

  // gi0 precompute: M=4096, N=1536, K=128
  {
    dim3 grid(1536/64, 4096/64);
    gemm_gi0<<<grid, 256, 0, stream>>>(state+1, 129, Wih0, 128, gi0, 1536, bih0, 128);
  }

  actor_fused<<<256, 512, 0, stream>>>(
      hprev, mask, Whh0, bhh0, Wih1, Whh1, bih1, bhh1, Wfc, bfc,
      gi0, H1, mb0l0, mb0l1, mb1l1, progS, progH, tick,
      out, out + (size_t)4096*4096);
}